// Round 4
// baseline (2853.888 us; speedup 1.0000x reference)
//
#include <hip/hip_runtime.h>

#define B_   4096
#define T_   1024
#define IN_  5
#define H_   16
#define L_   4
#define OUT_ 150

__device__ __forceinline__ float fast_rcp(float x) { return __builtin_amdgcn_rcpf(x); }

__device__ __forceinline__ float sigm(float v) {
    float e = __expf(-v);
    return fast_rcp(1.0f + e);
}

__device__ __forceinline__ float tanh_fast(float v) {
    float e = __expf(-2.0f * fabsf(v));
    float t = (1.0f - e) * fast_rcp(1.0f + e);
    return copysignf(t, v);
}

// ---- DPP lane-XOR permutes (all involutions -> direction-unambiguous) ----
// quad_perm encodings: [1,0,3,2]=0xB1 (xor1), [2,3,0,1]=0x4E (xor2),
// [3,2,1,0]=0x1B (xor3); row_mirror=0x140 (xor15), row_half_mirror=0x141 (xor7)
#define QP_X1   0xB1
#define QP_X2   0x4E
#define QP_X3   0x1B
#define ROW_MIR 0x140
#define ROW_HMIR 0x141

template <int CTRL>
__device__ __forceinline__ float dppf(float x) {
    int i = __float_as_int(x);
    return __int_as_float(__builtin_amdgcn_update_dpp(i, i, CTRL, 0xF, 0xF, false));
}

// dot over 16 lanes of a replicated vector: acc = sum_m w[m] * v[j^m] + init
// (w must be loaded xor-permuted: w[m] = W[row][j^m])
__device__ __forceinline__ float dotx(const float (&w)[H_], float v,
                                      float v7, float v15, float v8, float init) {
    float a = init, b = 0.0f, c = 0.0f, d = 0.0f;
    a = fmaf(v,              w[0],  a);
    b = fmaf(dppf<QP_X1>(v),  w[1],  b);
    c = fmaf(dppf<QP_X2>(v),  w[2],  c);
    d = fmaf(dppf<QP_X3>(v),  w[3],  d);
    a = fmaf(v7,             w[7],  a);
    b = fmaf(dppf<QP_X1>(v7), w[6],  b);
    c = fmaf(dppf<QP_X2>(v7), w[5],  c);
    d = fmaf(dppf<QP_X3>(v7), w[4],  d);
    a = fmaf(v15,            w[15], a);
    b = fmaf(dppf<QP_X1>(v15), w[14], b);
    c = fmaf(dppf<QP_X2>(v15), w[13], c);
    d = fmaf(dppf<QP_X3>(v15), w[12], d);
    a = fmaf(v8,             w[8],  a);
    b = fmaf(dppf<QP_X1>(v8), w[9],  b);
    c = fmaf(dppf<QP_X2>(v8), w[10], c);
    d = fmaf(dppf<QP_X3>(v8), w[11], d);
    return (a + b) + (c + d);
}

// 3 mirrors of a replicated vector: v7=v[j^7], v15=v[j^15], v8=v[j^8]
#define MIRRORS(V, V7, V15, V8)            \
    float V7  = dppf<ROW_HMIR>(V);         \
    float V15 = dppf<ROW_MIR>(V);          \
    float V8  = dppf<ROW_HMIR>(V15);

// waves_per_eu(2,2): min=max=2 waves/SIMD -> 256-VGPR budget, allocator must
// not spill to chase occupancy (launch_bounds(256,2) alone let it target 4
// waves and spill ~30 floats/thread -> WRITE_SIZE 33 MB, +18% dur).
__global__ __launch_bounds__(256)
__attribute__((amdgpu_waves_per_eu(2, 2)))
void gru_fused(
    const float* __restrict__ x_in,
    const float* __restrict__ Wih0, const float* __restrict__ Whh0,
    const float* __restrict__ bih0, const float* __restrict__ bhh0,
    const float* __restrict__ Wih1, const float* __restrict__ Whh1,
    const float* __restrict__ bih1, const float* __restrict__ bhh1,
    const float* __restrict__ Wih2, const float* __restrict__ Whh2,
    const float* __restrict__ bih2, const float* __restrict__ bhh2,
    const float* __restrict__ Wih3, const float* __restrict__ Whh3,
    const float* __restrict__ bih3, const float* __restrict__ bhh3,
    const float* __restrict__ fcw,  const float* __restrict__ fcb,
    float* __restrict__ out)
{
    // only used for the FC epilogue handoff now
    __shared__ float hs[4][L_][H_];

    const int wv   = threadIdx.x >> 6;
    const int lane = threadIdx.x & 63;
    const int g    = lane >> 4;          // 0=r,1=z,2=n rows; 3 duplicates n
    const int j    = lane & 15;
    const int row  = ((g < 3) ? g : 2) * H_ + j;

    const int b = blockIdx.x * 4 + wv;

    // ---- per-lane weight rows in registers; recurrent mats xor-permuted ----
    float wi0[IN_], wh0[H_];
    float wi1[H_], wh1[H_];
    float wi2[H_], wh2[H_];
    float wi3[H_], wh3[H_];
    float bi[4], bh[4];

#pragma unroll
    for (int k = 0; k < IN_; ++k) wi0[k] = Wih0[row * IN_ + k];
#pragma unroll
    for (int m = 0; m < H_; ++m) {
        const int jm = j ^ m;
        wh0[m] = Whh0[row * H_ + jm];
        wi1[m] = Wih1[row * H_ + jm];
        wh1[m] = Whh1[row * H_ + jm];
        wi2[m] = Wih2[row * H_ + jm];
        wh2[m] = Whh2[row * H_ + jm];
        wi3[m] = Wih3[row * H_ + jm];
        wh3[m] = Whh3[row * H_ + jm];
    }
    bi[0] = bih0[row]; bi[1] = bih1[row]; bi[2] = bih2[row]; bi[3] = bih3[row];
    bh[0] = bhh0[row]; bh[1] = bhh1[row]; bh[2] = bhh2[row]; bh[3] = bhh3[row];

    // replicated h state: every lane holds h^l_j for its j (identical across
    // the 4 lane-groups; the update formula preserves replication)
    float hold0 = 0.0f, hold1 = 0.0f, hold2 = 0.0f, hold3 = 0.0f;

    const float* xbase = x_in + (size_t)b * T_ * IN_;
    float xc0 = xbase[0], xc1 = xbase[1], xc2 = xbase[2], xc3 = xbase[3], xc4 = xbase[4];

    // gate tail (identical to the validated kernel; pure intra-wave)
#define LAYER_TAIL(BI, BH, HOLD)                                          \
    {                                                                     \
        float s_  = sigm(xg + hg);                                        \
        float rv_ = __shfl(s_, j, 64);                                    \
        float n_  = tanh_fast(fmaf(rv_, hg, xg));                         \
        float zv_ = __shfl(s_, 16 + j, 64);                               \
        float nv_ = __shfl(n_, 32 + j, 64);                               \
        HOLD = fmaf(zv_, HOLD - nv_, nv_);                                \
    }

#define STEP_LAYERS()                                                     \
    {                                                                     \
        { /* layer 0: x side = 5 wave-uniform scalars */                  \
            MIRRORS(hold0, h7, h15, h8)                                   \
            float xg = bi[0];                                             \
            xg = fmaf(wi0[0], xc0, xg);                                   \
            xg = fmaf(wi0[1], xc1, xg);                                   \
            xg = fmaf(wi0[2], xc2, xg);                                   \
            xg = fmaf(wi0[3], xc3, xg);                                   \
            xg = fmaf(wi0[4], xc4, xg);                                   \
            float hg = dotx(wh0, hold0, h7, h15, h8, bh[0]);              \
            LAYER_TAIL(bi[0], bh[0], hold0)                               \
        }                                                                 \
        { /* layer 1: x = fresh h^0 (replicated in-register) */           \
            MIRRORS(hold0, x7, x15, x8)                                   \
            MIRRORS(hold1, h7, h15, h8)                                   \
            float xg = dotx(wi1, hold0, x7, x15, x8, bi[1]);              \
            float hg = dotx(wh1, hold1, h7, h15, h8, bh[1]);              \
            LAYER_TAIL(bi[1], bh[1], hold1)                               \
        }                                                                 \
        { /* layer 2 */                                                   \
            MIRRORS(hold1, x7, x15, x8)                                   \
            MIRRORS(hold2, h7, h15, h8)                                   \
            float xg = dotx(wi2, hold1, x7, x15, x8, bi[2]);              \
            float hg = dotx(wh2, hold2, h7, h15, h8, bh[2]);              \
            LAYER_TAIL(bi[2], bh[2], hold2)                               \
        }                                                                 \
        { /* layer 3 */                                                   \
            MIRRORS(hold2, x7, x15, x8)                                   \
            MIRRORS(hold3, h7, h15, h8)                                   \
            float xg = dotx(wi3, hold2, x7, x15, x8, bi[3]);              \
            float hg = dotx(wh3, hold3, h7, h15, h8, bh[3]);              \
            LAYER_TAIL(bi[3], bh[3], hold3)                               \
        }                                                                 \
    }

#pragma unroll 1
    for (int t = 0; t < T_ - 1; ++t) {
        const float* xp = xbase + (t + 1) * IN_;
        float nx0 = xp[0], nx1 = xp[1], nx2 = xp[2], nx3 = xp[3], nx4 = xp[4];

        STEP_LAYERS()

        xc0 = nx0; xc1 = nx1; xc2 = nx2; xc3 = nx3; xc4 = nx4;
    }
    STEP_LAYERS()   // peeled final step (no prefetch)

#undef STEP_LAYERS
#undef LAYER_TAIL

    // ---- FC epilogue: park final h in LDS (all groups write same value) ----
    hs[wv][0][j] = hold0;
    hs[wv][1][j] = hold1;
    hs[wv][2][j] = hold2;
    hs[wv][3][j] = hold3;
    asm volatile("" ::: "memory");

    float hid[L_ * H_];
#pragma unroll
    for (int k = 0; k < H_; ++k) {
        hid[0 * H_ + k] = hs[wv][0][k];
        hid[1 * H_ + k] = hs[wv][1][k];
        hid[2 * H_ + k] = hs[wv][2][k];
        hid[3 * H_ + k] = hs[wv][3][k];
    }
    float* ob = out + (size_t)b * OUT_;
#pragma unroll
    for (int rep = 0; rep < 3; ++rep) {
        int o = lane + rep * 64;
        if (o < OUT_) {
            const float* wr = fcw + o * (L_ * H_);
            float acc = fcb[o];
#pragma unroll
            for (int k = 0; k < L_ * H_; ++k) acc = fmaf(wr[k], hid[k], acc);
            ob[o] = acc;
        }
    }
}

extern "C" void kernel_launch(void* const* d_in, const int* in_sizes, int n_in,
                              void* d_out, int out_size, void* d_ws, size_t ws_size,
                              hipStream_t stream) {
    const float* xin = (const float*)d_in[0];
    // d_in[1] = target_seq: unused by the reference output
    gru_fused<<<B_ / 4, 256, 0, stream>>>(
        xin,
        (const float*)d_in[2],  (const float*)d_in[3],  (const float*)d_in[4],  (const float*)d_in[5],
        (const float*)d_in[6],  (const float*)d_in[7],  (const float*)d_in[8],  (const float*)d_in[9],
        (const float*)d_in[10], (const float*)d_in[11], (const float*)d_in[12], (const float*)d_in[13],
        (const float*)d_in[14], (const float*)d_in[15], (const float*)d_in[16], (const float*)d_in[17],
        (const float*)d_in[18], (const float*)d_in[19],
        (float*)d_out);
}

// Round 5
// 2853.350 us; speedup vs baseline: 1.0002x; 1.0002x over previous
//
#include <hip/hip_runtime.h>

#define B_   4096
#define T_   1024
#define IN_  5
#define H_   16
#define L_   4
#define OUT_ 150

__device__ __forceinline__ float fast_rcp(float x) { return __builtin_amdgcn_rcpf(x); }

__device__ __forceinline__ float sigm(float v) {
    float e = __expf(-v);
    return fast_rcp(1.0f + e);
}

__device__ __forceinline__ float tanh_fast(float v) {
    float e = __expf(-2.0f * fabsf(v));
    float t = (1.0f - e) * fast_rcp(1.0f + e);
    return copysignf(t, v);
}

// ---- DPP lane-XOR permutes (involutions -> direction-unambiguous) ----
#define QP_X1    0xB1
#define QP_X2    0x4E
#define QP_X3    0x1B
#define ROW_MIR  0x140
#define ROW_HMIR 0x141

template <int CTRL>
__device__ __forceinline__ float dppf(float x) {
    int i = __float_as_int(x);
    return __int_as_float(__builtin_amdgcn_update_dpp(i, i, CTRL, 0xF, 0xF, false));
}

// acc = sum_m w[m] * v[j^m] + init, with w loaded xor-permuted (w[m]=W[row][j^m])
__device__ __forceinline__ float dotx(const float (&w)[H_], float v,
                                      float v7, float v15, float v8, float init) {
    float a = init, b = 0.0f, c = 0.0f, d = 0.0f;
    a = fmaf(v,               w[0],  a);
    b = fmaf(dppf<QP_X1>(v),  w[1],  b);
    c = fmaf(dppf<QP_X2>(v),  w[2],  c);
    d = fmaf(dppf<QP_X3>(v),  w[3],  d);
    a = fmaf(v7,              w[7],  a);
    b = fmaf(dppf<QP_X1>(v7), w[6],  b);
    c = fmaf(dppf<QP_X2>(v7), w[5],  c);
    d = fmaf(dppf<QP_X3>(v7), w[4],  d);
    a = fmaf(v15,             w[15], a);
    b = fmaf(dppf<QP_X1>(v15),w[14], b);
    c = fmaf(dppf<QP_X2>(v15),w[13], c);
    d = fmaf(dppf<QP_X3>(v15),w[12], d);
    a = fmaf(v8,              w[8],  a);
    b = fmaf(dppf<QP_X1>(v8), w[9],  b);
    c = fmaf(dppf<QP_X2>(v8), w[10], c);
    d = fmaf(dppf<QP_X3>(v8), w[11], d);
    return (a + b) + (c + d);
}

#define MIRRORS(V, V7, V15, V8)            \
    float V7  = dppf<ROW_HMIR>(V);         \
    float V15 = dppf<ROW_MIR>(V);          \
    float V8  = dppf<ROW_HMIR>(V15);

// Volatile asm def: cannot be rematerialized/sunk into the loop -> the weight
// VALUE must stay register-resident (budget 256 at 2 waves/EU; live ~165).
#define PIN(x) asm volatile("" : "+v"(x))

__global__ __launch_bounds__(256)
__attribute__((amdgpu_waves_per_eu(2, 2)))
void gru_fused(
    const float* __restrict__ x_in,
    const float* __restrict__ Wih0, const float* __restrict__ Whh0,
    const float* __restrict__ bih0, const float* __restrict__ bhh0,
    const float* __restrict__ Wih1, const float* __restrict__ Whh1,
    const float* __restrict__ bih1, const float* __restrict__ bhh1,
    const float* __restrict__ Wih2, const float* __restrict__ Whh2,
    const float* __restrict__ bih2, const float* __restrict__ bhh2,
    const float* __restrict__ Wih3, const float* __restrict__ Whh3,
    const float* __restrict__ bih3, const float* __restrict__ bhh3,
    const float* __restrict__ fcw,  const float* __restrict__ fcb,
    float* __restrict__ out)
{
    __shared__ float hs[4][L_][H_];   // FC-epilogue handoff only

    const int wv   = threadIdx.x >> 6;
    const int lane = threadIdx.x & 63;
    const int g    = lane >> 4;          // 0=r,1=z,2=n; 3 duplicates n
    const int j    = lane & 15;
    const int row  = ((g < 3) ? g : 2) * H_ + j;

    const int b = blockIdx.x * 4 + wv;

    float wi0[IN_], wh0[H_];
    float wi1[H_], wh1[H_];
    float wi2[H_], wh2[H_];
    float wi3[H_], wh3[H_];
    float bi[4], bh[4];

#pragma unroll
    for (int k = 0; k < IN_; ++k) wi0[k] = Wih0[row * IN_ + k];
#pragma unroll
    for (int m = 0; m < H_; ++m) {
        const int jm = j ^ m;
        wh0[m] = Whh0[row * H_ + jm];
        wi1[m] = Wih1[row * H_ + jm];
        wh1[m] = Whh1[row * H_ + jm];
        wi2[m] = Wih2[row * H_ + jm];
        wh2[m] = Whh2[row * H_ + jm];
        wi3[m] = Wih3[row * H_ + jm];
        wh3[m] = Whh3[row * H_ + jm];
    }
    bi[0] = bih0[row]; bi[1] = bih1[row]; bi[2] = bih2[row]; bi[3] = bih3[row];
    bh[0] = bhh0[row]; bh[1] = bhh1[row]; bh[2] = bhh2[row]; bh[3] = bhh3[row];

    // ---- pin everything the loop consumes (defeat load-remat) ----
#pragma unroll
    for (int k = 0; k < IN_; ++k) PIN(wi0[k]);
#pragma unroll
    for (int m = 0; m < H_; ++m) {
        PIN(wh0[m]); PIN(wi1[m]); PIN(wh1[m]); PIN(wi2[m]);
        PIN(wh2[m]); PIN(wi3[m]); PIN(wh3[m]);
    }
#pragma unroll
    for (int k = 0; k < 4; ++k) { PIN(bi[k]); PIN(bh[k]); }

    // replicated h state (identical across the 4 lane-groups; update preserves it)
    float hold0 = 0.0f, hold1 = 0.0f, hold2 = 0.0f, hold3 = 0.0f;

    const float* xbase = x_in + (size_t)b * T_ * IN_;
    float xc0 = xbase[0], xc1 = xbase[1], xc2 = xbase[2], xc3 = xbase[3], xc4 = xbase[4];

#define LAYER_TAIL(HOLD)                                                  \
    {                                                                     \
        float s_  = sigm(xg + hg);                                        \
        float rv_ = __shfl(s_, j, 64);                                    \
        float n_  = tanh_fast(fmaf(rv_, hg, xg));                         \
        float zv_ = __shfl(s_, 16 + j, 64);                               \
        float nv_ = __shfl(n_, 32 + j, 64);                               \
        HOLD = fmaf(zv_, HOLD - nv_, nv_);                                \
    }

#define STEP_LAYERS()                                                     \
    {                                                                     \
        { /* layer 0: x side = 5 wave-uniform scalars */                  \
            MIRRORS(hold0, h7, h15, h8)                                   \
            float xg = bi[0];                                             \
            xg = fmaf(wi0[0], xc0, xg);                                   \
            xg = fmaf(wi0[1], xc1, xg);                                   \
            xg = fmaf(wi0[2], xc2, xg);                                   \
            xg = fmaf(wi0[3], xc3, xg);                                   \
            xg = fmaf(wi0[4], xc4, xg);                                   \
            float hg = dotx(wh0, hold0, h7, h15, h8, bh[0]);              \
            LAYER_TAIL(hold0)                                             \
        }                                                                 \
        { /* layer 1 */                                                   \
            MIRRORS(hold0, x7, x15, x8)                                   \
            MIRRORS(hold1, h7, h15, h8)                                   \
            float xg = dotx(wi1, hold0, x7, x15, x8, bi[1]);              \
            float hg = dotx(wh1, hold1, h7, h15, h8, bh[1]);              \
            LAYER_TAIL(hold1)                                             \
        }                                                                 \
        { /* layer 2 */                                                   \
            MIRRORS(hold1, x7, x15, x8)                                   \
            MIRRORS(hold2, h7, h15, h8)                                   \
            float xg = dotx(wi2, hold1, x7, x15, x8, bi[2]);              \
            float hg = dotx(wh2, hold2, h7, h15, h8, bh[2]);              \
            LAYER_TAIL(hold2)                                             \
        }                                                                 \
        { /* layer 3 */                                                   \
            MIRRORS(hold2, x7, x15, x8)                                   \
            MIRRORS(hold3, h7, h15, h8)                                   \
            float xg = dotx(wi3, hold2, x7, x15, x8, bi[3]);              \
            float hg = dotx(wh3, hold3, h7, h15, h8, bh[3]);              \
            LAYER_TAIL(hold3)                                             \
        }                                                                 \
    }

#pragma unroll 1
    for (int t = 0; t < T_ - 1; ++t) {
        const float* xp = xbase + (t + 1) * IN_;
        float nx0 = xp[0], nx1 = xp[1], nx2 = xp[2], nx3 = xp[3], nx4 = xp[4];

        STEP_LAYERS()

        xc0 = nx0; xc1 = nx1; xc2 = nx2; xc3 = nx3; xc4 = nx4;
    }
    STEP_LAYERS()   // peeled final step

#undef STEP_LAYERS
#undef LAYER_TAIL

    // ---- FC epilogue ----
    hs[wv][0][j] = hold0;
    hs[wv][1][j] = hold1;
    hs[wv][2][j] = hold2;
    hs[wv][3][j] = hold3;
    asm volatile("" ::: "memory");

    float hid[L_ * H_];
#pragma unroll
    for (int k = 0; k < H_; ++k) {
        hid[0 * H_ + k] = hs[wv][0][k];
        hid[1 * H_ + k] = hs[wv][1][k];
        hid[2 * H_ + k] = hs[wv][2][k];
        hid[3 * H_ + k] = hs[wv][3][k];
    }
    float* ob = out + (size_t)b * OUT_;
#pragma unroll
    for (int rep = 0; rep < 3; ++rep) {
        int o = lane + rep * 64;
        if (o < OUT_) {
            const float* wr = fcw + o * (L_ * H_);
            float acc = fcb[o];
#pragma unroll
            for (int k = 0; k < L_ * H_; ++k) acc = fmaf(wr[k], hid[k], acc);
            ob[o] = acc;
        }
    }
}

extern "C" void kernel_launch(void* const* d_in, const int* in_sizes, int n_in,
                              void* d_out, int out_size, void* d_ws, size_t ws_size,
                              hipStream_t stream) {
    const float* xin = (const float*)d_in[0];
    // d_in[1] = target_seq: unused by the reference output
    gru_fused<<<B_ / 4, 256, 0, stream>>>(
        xin,
        (const float*)d_in[2],  (const float*)d_in[3],  (const float*)d_in[4],  (const float*)d_in[5],
        (const float*)d_in[6],  (const float*)d_in[7],  (const float*)d_in[8],  (const float*)d_in[9],
        (const float*)d_in[10], (const float*)d_in[11], (const float*)d_in[12], (const float*)d_in[13],
        (const float*)d_in[14], (const float*)d_in[15], (const float*)d_in[16], (const float*)d_in[17],
        (const float*)d_in[18], (const float*)d_in[19],
        (float*)d_out);
}

// Round 6
// 1691.227 us; speedup vs baseline: 1.6875x; 1.6871x over previous
//
#include <hip/hip_runtime.h>

#define B_   4096
#define T_   1024
#define IN_  5
#define H_   16
#define L_   4
#define OUT_ 150
#define NB   16     // batches per wave
#define LDW  20     // LDS row stride in u32: 16->20 kills bank conflicts, keeps 16B align

typedef int   v4i __attribute__((ext_vector_type(4)));
typedef float v4f __attribute__((ext_vector_type(4)));
typedef short v8h __attribute__((ext_vector_type(8)));

union Frag { v4i i; v8h h; };

__device__ __forceinline__ float fast_rcp(float x) { return __builtin_amdgcn_rcpf(x); }
__device__ __forceinline__ float sigm(float v) {
    float e = __expf(-v);
    return fast_rcp(1.0f + e);
}
__device__ __forceinline__ float tanh_fast(float v) {
    float e = __expf(-2.0f * fabsf(v));
    float t = (1.0f - e) * fast_rcp(1.0f + e);
    return copysignf(t, v);
}

// split v into bf16 hi (truncated) + bf16 lo (residual), packed lo16=hi-part, hi16=lo-part
__device__ __forceinline__ unsigned packsplit(float v) {
    unsigned uh = __float_as_uint(v);
    float ah = __uint_as_float(uh & 0xFFFF0000u);
    float al = v - ah;                       // exact
    return (uh >> 16) | (__float_as_uint(al) & 0xFFFF0000u);
}

#define MEMBAR() asm volatile("" ::: "memory")
#define PIN(x)   asm volatile("" : "+v"(x))

__device__ __forceinline__ v4f mfma16(v8h a, v8h b, v4f c) {
    return __builtin_amdgcn_mfma_f32_16x16x32_bf16(a, b, c, 0, 0, 0);
}

__global__ __launch_bounds__(64)
__attribute__((amdgpu_waves_per_eu(1, 1)))
void gru_mfma(
    const float* __restrict__ x_in,
    const float* __restrict__ Wih0, const float* __restrict__ Whh0,
    const float* __restrict__ bih0, const float* __restrict__ bhh0,
    const float* __restrict__ Wih1, const float* __restrict__ Whh1,
    const float* __restrict__ bih1, const float* __restrict__ bhh1,
    const float* __restrict__ Wih2, const float* __restrict__ Whh2,
    const float* __restrict__ bih2, const float* __restrict__ bhh2,
    const float* __restrict__ Wih3, const float* __restrict__ Whh3,
    const float* __restrict__ bih3, const float* __restrict__ bhh3,
    const float* __restrict__ fcw,  const float* __restrict__ fcb,
    float* __restrict__ out)
{
    // h^l state, packed split-bf16, [batch][comp] with padded stride
    __shared__ int hb[L_][NB * LDW];
    __shared__ int xls[NB * LDW];           // x_t staging, comps 5..15 stay 0

    const int lane = threadIdx.x & 63;
    const int q    = lane >> 4;             // k-block / row-group selector
    const int mm   = lane & 15;             // A-row (batch) / D-col (j) index
    const int b0   = blockIdx.x * NB;

    const float* Wih[L_] = {Wih0, Wih1, Wih2, Wih3};
    const float* Whh[L_] = {Whh0, Whh1, Whh2, Whh3};
    const float* bih[L_] = {bih0, bih1, bih2, bih3};
    const float* bhh[L_] = {bhh0, bhh1, bhh2, bhh3};

    // ---- zero LDS ----
    {
        int* flat = &hb[0][0];
        for (int i = lane; i < L_ * NB * LDW; i += 64) flat[i] = 0;
        for (int i = lane; i < NB * LDW; i += 64) xls[i] = 0;
    }
    MEMBAR();

    // ---- build B fragments (register-resident, split bf16) ----
    // B[k][n], K=32: k<16 = x side (layer0: only k<5 used), k>=16 = h side.
    // tiles: 0=r, 1=z, 2=n_x (h side 0), 3=n_h (x side 0)
    Frag Bh[L_][4], Bl[L_][4];
    float bias[L_][4];
#pragma unroll
    for (int l = 0; l < L_; ++l) {
        const int KX = (l == 0) ? IN_ : H_;
        const float* wi = Wih[l];
        const float* wh = Whh[l];
#pragma unroll
        for (int tile = 0; tile < 4; ++tile) {
            const int rowbase = (tile == 0) ? 0 : (tile == 1) ? 16 : 32;
            const int r = rowbase + mm;     // weight row (gate output n = mm)
            float vals[8];
#pragma unroll
            for (int e = 0; e < 8; ++e) {
                const int k = q * 8 + e;
                float v = 0.0f;
                if (k < 16) { if (tile != 3 && k < KX) v = wi[r * KX + k]; }
                else        { if (tile != 2)           v = wh[r * H_ + (k - 16)]; }
                vals[e] = v;
            }
#pragma unroll
            for (int d = 0; d < 4; ++d) {
                unsigned p0 = packsplit(vals[2 * d]);
                unsigned p1 = packsplit(vals[2 * d + 1]);
                Bh[l][tile].i[d] = (int)((p0 & 0xFFFFu) | (p1 << 16));
                Bl[l][tile].i[d] = (int)((p0 >> 16) | (p1 & 0xFFFF0000u));
            }
        }
        bias[l][0] = bih[l][mm] + bhh[l][mm];
        bias[l][1] = bih[l][16 + mm] + bhh[l][16 + mm];
        bias[l][2] = bih[l][32 + mm];
        bias[l][3] = bhh[l][32 + mm];
    }
    // pin fragment values (prologue-only cost; insurance against remat/spill)
#pragma unroll
    for (int l = 0; l < L_; ++l)
#pragma unroll
        for (int tile = 0; tile < 4; ++tile)
#pragma unroll
            for (int d = 0; d < 4; ++d) {
                int th = Bh[l][tile].i[d]; PIN(th); Bh[l][tile].i[d] = th;
                int tl = Bl[l][tile].i[d]; PIN(tl); Bl[l][tile].i[d] = tl;
            }

    // ---- x prefetch/staging: lane (q,mm) owns x[b0+mm][t][q] (+[4] for q==0) ----
    const float* xptr = x_in + (size_t)(b0 + mm) * T_ * IN_;
    {
        float xa = xptr[q];
        float xb = (q == 0) ? xptr[4] : 0.0f;
        xls[mm * LDW + q] = (int)packsplit(xa);
        if (q == 0) xls[mm * LDW + 4] = (int)packsplit(xb);
    }
    MEMBAR();
    float xa = xptr[IN_ + q];
    float xb = (q == 0) ? xptr[IN_ + 4] : 0.0f;

    float hold[L_][4] = {};   // exact fp32 h per (layer, batch-reg)

#pragma unroll 1
    for (int t = 0; t < T_; ++t) {
#pragma unroll
        for (int l = 0; l < L_; ++l) {
            // ---- A fragment: rows=batch(mm), k = q*8+e ----
            const int* xsrc = (l == 0) ? xls : &hb[l - 1][0];
            const int* asrc = (q < 2) ? xsrc : &hb[l][0];
            const int ao = mm * LDW + (q & 1) * 8;
            int u0 = asrc[ao + 0], u1 = asrc[ao + 1], u2 = asrc[ao + 2], u3 = asrc[ao + 3];
            int u4 = asrc[ao + 4], u5 = asrc[ao + 5], u6 = asrc[ao + 6], u7 = asrc[ao + 7];

            Frag Ah, Al;
            Ah.i[0] = (int)__builtin_amdgcn_perm((unsigned)u1, (unsigned)u0, 0x05040100u);
            Ah.i[1] = (int)__builtin_amdgcn_perm((unsigned)u3, (unsigned)u2, 0x05040100u);
            Ah.i[2] = (int)__builtin_amdgcn_perm((unsigned)u5, (unsigned)u4, 0x05040100u);
            Ah.i[3] = (int)__builtin_amdgcn_perm((unsigned)u7, (unsigned)u6, 0x05040100u);
            Al.i[0] = (int)__builtin_amdgcn_perm((unsigned)u1, (unsigned)u0, 0x07060302u);
            Al.i[1] = (int)__builtin_amdgcn_perm((unsigned)u3, (unsigned)u2, 0x07060302u);
            Al.i[2] = (int)__builtin_amdgcn_perm((unsigned)u5, (unsigned)u4, 0x07060302u);
            Al.i[3] = (int)__builtin_amdgcn_perm((unsigned)u7, (unsigned)u6, 0x07060302u);

            // ---- 12 MFMA: 4 tiles x (Al*Bh + Ah*Bl + Ah*Bh) ----
            v4f a0 = {bias[l][0], bias[l][0], bias[l][0], bias[l][0]};
            v4f a1 = {bias[l][1], bias[l][1], bias[l][1], bias[l][1]};
            v4f a2 = {bias[l][2], bias[l][2], bias[l][2], bias[l][2]};
            v4f a3 = {bias[l][3], bias[l][3], bias[l][3], bias[l][3]};
            a0 = mfma16(Al.h, Bh[l][0].h, a0);
            a1 = mfma16(Al.h, Bh[l][1].h, a1);
            a2 = mfma16(Al.h, Bh[l][2].h, a2);
            a3 = mfma16(Al.h, Bh[l][3].h, a3);
            a0 = mfma16(Ah.h, Bl[l][0].h, a0);
            a1 = mfma16(Ah.h, Bl[l][1].h, a1);
            a2 = mfma16(Ah.h, Bl[l][2].h, a2);
            a3 = mfma16(Ah.h, Bl[l][3].h, a3);
            a0 = mfma16(Ah.h, Bh[l][0].h, a0);
            a1 = mfma16(Ah.h, Bh[l][1].h, a1);
            a2 = mfma16(Ah.h, Bh[l][2].h, a2);
            a3 = mfma16(Ah.h, Bh[l][3].h, a3);

            // ---- tail: lane holds (batch=q*4+reg, j=mm) for all 4 gate tiles ----
#pragma unroll
            for (int reg = 0; reg < 4; ++reg) {
                float r = sigm(a0[reg]);
                float z = sigm(a1[reg]);
                float n = tanh_fast(fmaf(r, a3[reg], a2[reg]));
                float h = fmaf(z, hold[l][reg] - n, n);
                hold[l][reg] = h;
                hb[l][(q * 4 + reg) * LDW + mm] = (int)packsplit(h);
            }
            MEMBAR();
        }

        // ---- x pipeline: issue t+2 loads, stage t+1 ----
        const int tn = (t + 2 < T_) ? (t + 2) : (T_ - 1);
        float na = xptr[tn * IN_ + q];
        float nb = (q == 0) ? xptr[tn * IN_ + 4] : 0.0f;
        xls[mm * LDW + q] = (int)packsplit(xa);
        if (q == 0) xls[mm * LDW + 4] = (int)packsplit(xb);
        MEMBAR();
        xa = na; xb = nb;
    }

    // ---- FC epilogue: out[b][o] = fcb[o] + sum_k fcw[o][k] * hidden[b][k] ----
#pragma unroll
    for (int rep = 0; rep < 3; ++rep) {
        const int o = lane + rep * 64;
        if (o < OUT_) {
            float wr[L_ * H_];
#pragma unroll
            for (int k = 0; k < L_ * H_; ++k) wr[k] = fcw[o * (L_ * H_) + k];
            const float fb = fcb[o];
            for (int m = 0; m < NB; ++m) {
                float acc = fb;
#pragma unroll
                for (int k = 0; k < L_ * H_; ++k) {
                    const int l = k >> 4, j = k & 15;
                    unsigned u = (unsigned)hb[l][m * LDW + j];
                    float a = __uint_as_float(u << 16) + __uint_as_float(u & 0xFFFF0000u);
                    acc = fmaf(wr[k], a, acc);
                }
                out[(size_t)(b0 + m) * OUT_ + o] = acc;
            }
        }
    }
}

extern "C" void kernel_launch(void* const* d_in, const int* in_sizes, int n_in,
                              void* d_out, int out_size, void* d_ws, size_t ws_size,
                              hipStream_t stream) {
    const float* xin = (const float*)d_in[0];
    // d_in[1] = target_seq: unused by the reference output
    gru_mfma<<<B_ / NB, 64, 0, stream>>>(
        xin,
        (const float*)d_in[2],  (const float*)d_in[3],  (const float*)d_in[4],  (const float*)d_in[5],
        (const float*)d_in[6],  (const float*)d_in[7],  (const float*)d_in[8],  (const float*)d_in[9],
        (const float*)d_in[10], (const float*)d_in[11], (const float*)d_in[12], (const float*)d_in[13],
        (const float*)d_in[14], (const float*)d_in[15], (const float*)d_in[16], (const float*)d_in[17],
        (const float*)d_in[18], (const float*)d_in[19],
        (float*)d_out);
}

// Round 7
// 682.829 us; speedup vs baseline: 4.1795x; 2.4768x over previous
//
#include <hip/hip_runtime.h>

#define B_   4096
#define T_   1024
#define IN_  5
#define H_   16
#define L_   4
#define OUT_ 150
#define NB   16     // batches per block (= MFMA M)
#define LDW  20     // LDS row stride in u32 (pad vs 16)

typedef int   v4i __attribute__((ext_vector_type(4)));
typedef float v4f __attribute__((ext_vector_type(4)));
typedef short v8h __attribute__((ext_vector_type(8)));

union Frag { v4i i; v8h h; };

__device__ __forceinline__ float fast_rcp(float x) { return __builtin_amdgcn_rcpf(x); }
__device__ __forceinline__ float sigm(float v) {
    float e = __expf(-v);
    return fast_rcp(1.0f + e);
}
__device__ __forceinline__ float tanh_fast(float v) {
    float e = __expf(-2.0f * fabsf(v));
    float t = (1.0f - e) * fast_rcp(1.0f + e);
    return copysignf(t, v);
}

// split v into bf16 hi (truncated) + exact residual lo; pack as lo16=hi, hi16=lo
__device__ __forceinline__ unsigned packsplit(float v) {
    unsigned uh = __float_as_uint(v);
    float ah = __uint_as_float(uh & 0xFFFF0000u);
    float al = v - ah;                       // exact
    return (uh >> 16) | (__float_as_uint(al) & 0xFFFF0000u);
}

__device__ __forceinline__ v4f mfma16(v8h a, v8h b, v4f c) {
    return __builtin_amdgcn_mfma_f32_16x16x32_bf16(a, b, c, 0, 0, 0);
}

__global__ __launch_bounds__(256)
void gru_pipe(
    const float* __restrict__ x_in,
    const float* __restrict__ Wih0, const float* __restrict__ Whh0,
    const float* __restrict__ bih0, const float* __restrict__ bhh0,
    const float* __restrict__ Wih1, const float* __restrict__ Whh1,
    const float* __restrict__ bih1, const float* __restrict__ bhh1,
    const float* __restrict__ Wih2, const float* __restrict__ Whh2,
    const float* __restrict__ bih2, const float* __restrict__ bhh2,
    const float* __restrict__ Wih3, const float* __restrict__ Whh3,
    const float* __restrict__ bih3, const float* __restrict__ bhh3,
    const float* __restrict__ fcw,  const float* __restrict__ fcb,
    float* __restrict__ out)
{
    // h^l packed split-bf16, double-buffered by tick parity
    __shared__ int   hbuf[L_][2][NB * LDW];
    __shared__ float fchid[NB][L_ * H_];     // exact fp32 final h for FC

    const int tid  = threadIdx.x;
    const int w    = tid >> 6;               // wave index == layer index
    const int lane = tid & 63;
    const int q    = lane >> 4;              // k-block / batch-row-group selector
    const int mm   = lane & 15;              // A-row (batch) / D-col (j) index
    const int b0   = blockIdx.x * NB;

    // ---- this wave's weight pointers ----
    const float *wi, *wh, *bip, *bhp;
    if      (w == 0) { wi = Wih0; wh = Whh0; bip = bih0; bhp = bhh0; }
    else if (w == 1) { wi = Wih1; wh = Whh1; bip = bih1; bhp = bhh1; }
    else if (w == 2) { wi = Wih2; wh = Whh2; bip = bih2; bhp = bhh2; }
    else             { wi = Wih3; wh = Whh3; bip = bih3; bhp = bhh3; }
    const int KX = (w == 0) ? IN_ : H_;

    // ---- zero hbuf (both parities) ----
    for (int i = tid; i < L_ * 2 * NB * LDW; i += 256) (&hbuf[0][0][0])[i] = 0;

    // ---- B fragments for THIS layer only (register-resident, split bf16) ----
    // B[k][n], K=32: k<16 = x side, k>=16 = h side. tiles: 0=r,1=z,2=n_x,3=n_h
    Frag Bh[4], Bl[4];
    float bias[4];
#pragma unroll
    for (int tile = 0; tile < 4; ++tile) {
        const int rowbase = (tile == 0) ? 0 : (tile == 1) ? 16 : 32;
        const int r = rowbase + mm;
        float vals[8];
#pragma unroll
        for (int e = 0; e < 8; ++e) {
            const int k = q * 8 + e;
            float v = 0.0f;
            if (k < 16) { if (tile != 3 && k < KX) v = wi[r * KX + k]; }
            else        { if (tile != 2)           v = wh[r * H_ + (k - 16)]; }
            vals[e] = v;
        }
#pragma unroll
        for (int d = 0; d < 4; ++d) {
            unsigned p0 = packsplit(vals[2 * d]);
            unsigned p1 = packsplit(vals[2 * d + 1]);
            Bh[tile].i[d] = (int)((p0 & 0xFFFFu) | (p1 << 16));
            Bl[tile].i[d] = (int)((p0 >> 16) | (p1 & 0xFFFF0000u));
        }
    }
    bias[0] = bip[mm]      + bhp[mm];
    bias[1] = bip[16 + mm] + bhp[16 + mm];
    bias[2] = bip[32 + mm];
    bias[3] = bhp[32 + mm];

    __syncthreads();

    // ---- wave-0 x state: lane (q==0, mm) owns x[b0+mm][t][0..4] ----
    const float* xptr = x_in + (size_t)(b0 + mm) * T_ * IN_;
    float xv0 = 0, xv1 = 0, xv2 = 0, xv3 = 0, xv4 = 0;
    if (w == 0 && q == 0) { xv0 = xptr[0]; xv1 = xptr[1]; xv2 = xptr[2]; xv3 = xptr[3]; xv4 = xptr[4]; }

    float hold[4] = {0.0f, 0.0f, 0.0f, 0.0f};   // exact fp32 h, batch = q*4+reg

    // ---- skewed pipeline: tick k, wave w does time t = k - w ----
#pragma unroll 1
    for (int k = 0; k < T_ + L_ - 1; ++k) {
        const int t = k - w;
        if (0 <= t && t < T_) {
            // prefetch x_{t+1} (wave 0 only; issued first so the barrier's
            // vmcnt drain is covered by this tick's compute)
            float nx0, nx1, nx2, nx3, nx4;
            if (w == 0 && q == 0) {
                const int tn = (t + 1 < T_) ? (t + 1) : (T_ - 1);
                const float* xp = xptr + tn * IN_;
                nx0 = xp[0]; nx1 = xp[1]; nx2 = xp[2]; nx3 = xp[3]; nx4 = xp[4];
            }

            const int rp = (k - 1) & 1;          // parity holding inputs (t-1 / upstream t)

            // ---- A fragment: rows = batch(mm), k-slot = q*8+e ----
            Frag Ah, Al;
            if (w == 0 && q < 2) {
                if (q == 0) {
                    unsigned p0 = packsplit(xv0), p1 = packsplit(xv1);
                    unsigned p2 = packsplit(xv2), p3 = packsplit(xv3);
                    unsigned p4 = packsplit(xv4);
                    Ah.i[0] = (int)((p0 & 0xFFFFu) | (p1 << 16));
                    Al.i[0] = (int)((p0 >> 16) | (p1 & 0xFFFF0000u));
                    Ah.i[1] = (int)((p2 & 0xFFFFu) | (p3 << 16));
                    Al.i[1] = (int)((p2 >> 16) | (p3 & 0xFFFF0000u));
                    Ah.i[2] = (int)(p4 & 0xFFFFu);
                    Al.i[2] = (int)(p4 >> 16);
                    Ah.i[3] = 0; Al.i[3] = 0;
                } else {
                    Ah.i[0] = Ah.i[1] = Ah.i[2] = Ah.i[3] = 0;
                    Al.i[0] = Al.i[1] = Al.i[2] = Al.i[3] = 0;
                }
            } else {
                const int up = (w > 0) ? (w - 1) : 0;
                const int* asrc = (q < 2) ? &hbuf[up][rp][0] : &hbuf[w][rp][0];
                const int ao = mm * LDW + (q & 1) * 8;
                int u0 = asrc[ao + 0], u1 = asrc[ao + 1], u2 = asrc[ao + 2], u3 = asrc[ao + 3];
                int u4 = asrc[ao + 4], u5 = asrc[ao + 5], u6 = asrc[ao + 6], u7 = asrc[ao + 7];
                Ah.i[0] = (int)__builtin_amdgcn_perm((unsigned)u1, (unsigned)u0, 0x05040100u);
                Ah.i[1] = (int)__builtin_amdgcn_perm((unsigned)u3, (unsigned)u2, 0x05040100u);
                Ah.i[2] = (int)__builtin_amdgcn_perm((unsigned)u5, (unsigned)u4, 0x05040100u);
                Ah.i[3] = (int)__builtin_amdgcn_perm((unsigned)u7, (unsigned)u6, 0x05040100u);
                Al.i[0] = (int)__builtin_amdgcn_perm((unsigned)u1, (unsigned)u0, 0x07060302u);
                Al.i[1] = (int)__builtin_amdgcn_perm((unsigned)u3, (unsigned)u2, 0x07060302u);
                Al.i[2] = (int)__builtin_amdgcn_perm((unsigned)u5, (unsigned)u4, 0x07060302u);
                Al.i[3] = (int)__builtin_amdgcn_perm((unsigned)u7, (unsigned)u6, 0x07060302u);
            }

            // ---- 12 MFMA: 4 tiles x (Al*Bh + Ah*Bl + Ah*Bh) ----
            v4f a0 = {bias[0], bias[0], bias[0], bias[0]};
            v4f a1 = {bias[1], bias[1], bias[1], bias[1]};
            v4f a2 = {bias[2], bias[2], bias[2], bias[2]};
            v4f a3 = {bias[3], bias[3], bias[3], bias[3]};
            a0 = mfma16(Al.h, Bh[0].h, a0);
            a1 = mfma16(Al.h, Bh[1].h, a1);
            a2 = mfma16(Al.h, Bh[2].h, a2);
            a3 = mfma16(Al.h, Bh[3].h, a3);
            a0 = mfma16(Ah.h, Bl[0].h, a0);
            a1 = mfma16(Ah.h, Bl[1].h, a1);
            a2 = mfma16(Ah.h, Bl[2].h, a2);
            a3 = mfma16(Ah.h, Bl[3].h, a3);
            a0 = mfma16(Ah.h, Bh[0].h, a0);
            a1 = mfma16(Ah.h, Bh[1].h, a1);
            a2 = mfma16(Ah.h, Bh[2].h, a2);
            a3 = mfma16(Ah.h, Bh[3].h, a3);

            // ---- gate tail: lane holds (batch=q*4+reg, j=mm) ----
            const int wp = k & 1;
#pragma unroll
            for (int reg = 0; reg < 4; ++reg) {
                float r = sigm(a0[reg]);
                float z = sigm(a1[reg]);
                float n = tanh_fast(fmaf(r, a3[reg], a2[reg]));
                float h = fmaf(z, hold[reg] - n, n);
                hold[reg] = h;
                hbuf[w][wp][(q * 4 + reg) * LDW + mm] = (int)packsplit(h);
            }

            if (w == 0 && q == 0) { xv0 = nx0; xv1 = nx1; xv2 = nx2; xv3 = nx3; xv4 = nx4; }
        }
        __syncthreads();
    }

    // ---- FC epilogue: exact fp32 hidden from hold regs ----
#pragma unroll
    for (int reg = 0; reg < 4; ++reg)
        fchid[q * 4 + reg][w * H_ + mm] = hold[reg];
    __syncthreads();

    for (int o = tid; o < NB * OUT_; o += 256) {
        const int m = o / OUT_, oc = o % OUT_;
        float acc = fcb[oc];
#pragma unroll
        for (int kk = 0; kk < L_ * H_; ++kk)
            acc = fmaf(fcw[oc * (L_ * H_) + kk], fchid[m][kk], acc);
        out[(size_t)(b0 + m) * OUT_ + oc] = acc;
    }
}

extern "C" void kernel_launch(void* const* d_in, const int* in_sizes, int n_in,
                              void* d_out, int out_size, void* d_ws, size_t ws_size,
                              hipStream_t stream) {
    const float* xin = (const float*)d_in[0];
    // d_in[1] = target_seq: unused by the reference output
    gru_pipe<<<B_ / NB, 256, 0, stream>>>(
        xin,
        (const float*)d_in[2],  (const float*)d_in[3],  (const float*)d_in[4],  (const float*)d_in[5],
        (const float*)d_in[6],  (const float*)d_in[7],  (const float*)d_in[8],  (const float*)d_in[9],
        (const float*)d_in[10], (const float*)d_in[11], (const float*)d_in[12], (const float*)d_in[13],
        (const float*)d_in[14], (const float*)d_in[15], (const float*)d_in[16], (const float*)d_in[17],
        (const float*)d_in[18], (const float*)d_in[19],
        (float*)d_out);
}